// Round 6
// baseline (467.108 us; speedup 1.0000x reference)
//
#include <hip/hip_runtime.h>
#include <math.h>

#define BB 2
#define LL 2048
#define EE 2048
#define HH 16
#define HD 128
#define N3E (3*EE)   // 6144

typedef __attribute__((ext_vector_type(8))) short  bf16x8;
typedef __attribute__((ext_vector_type(4))) float  f32x4;

__device__ __forceinline__ ushort f2bf(float f) {
    union { float f; unsigned u; } v; v.f = f;
    unsigned u = v.u + 0x7FFFu + ((v.u >> 16) & 1u);   // RNE
    return (ushort)(u >> 16);
}
__device__ __forceinline__ float bf2f(ushort u) {
    union { unsigned u; float f; } v; v.u = ((unsigned)u) << 16;
    return v.f;
}

// ================= fused pre-pass: cvt(x) + transpose(W_attn) + transpose(W_proj) =================
// blocks [0,4096): cvt; [4096,16384): W_attn transpose (192x64); [16384,20480): W_proj (64x64)
#define NB_CVT 4096
#define NB_T1  12288
#define NB_T2  4096

__device__ __forceinline__ void tr_block(const float* __restrict__ in,
                                         ushort* __restrict__ out,
                                         int R, int Ccol, int bx, int by,
                                         float (*tile)[33], int t) {
    int c0 = bx * 32, r0 = by * 32;
    int lr = t >> 5, lc = t & 31;
    #pragma unroll
    for (int i = 0; i < 4; ++i)
        tile[lr + i * 8][lc] = in[(size_t)(r0 + lr + i * 8) * Ccol + c0 + lc];
    __syncthreads();
    #pragma unroll
    for (int i = 0; i < 4; ++i)
        out[(size_t)(c0 + lr + i * 8) * R + r0 + lc] = f2bf(tile[lc][lr + i * 8]);
}

__global__ __launch_bounds__(256) void pre_all(const float* __restrict__ x,
                                               ushort* __restrict__ xb,
                                               const float* __restrict__ W_attn,
                                               ushort* __restrict__ Wat,
                                               const float* __restrict__ W_proj,
                                               ushort* __restrict__ Wpt) {
    __shared__ float tile[32][33];
    int bid = blockIdx.x;
    int t = threadIdx.x;
    if (bid < NB_CVT) {
        int i = (bid * 256 + t) * 8;
        float4 a = *(const float4*)(x + i);
        float4 b = *(const float4*)(x + i + 4);
        ushort4 p0 = { f2bf(a.x), f2bf(a.y), f2bf(a.z), f2bf(a.w) };
        ushort4 p1 = { f2bf(b.x), f2bf(b.y), f2bf(b.z), f2bf(b.w) };
        *(ushort4*)(xb + i)     = p0;
        *(ushort4*)(xb + i + 4) = p1;
    } else if (bid < NB_CVT + NB_T1) {
        int lb = bid - NB_CVT;
        tr_block(W_attn, Wat, EE, N3E, lb % (N3E / 32), lb / (N3E / 32), tile, t);
    } else {
        int lb = bid - NB_CVT - NB_T1;
        tr_block(W_proj, Wpt, EE, EE, lb % (EE / 32), lb / (EE / 32), tile, t);
    }
}

// ========== 256x128 8-wave GEMM, ring-4, counted-vmcnt (round-5 kernel, FROZEN) ==========
template<int WRITE_BF16>
__global__ __launch_bounds__(512, 2) void gemm_ktile(const ushort* __restrict__ A,
                                                     const ushort* __restrict__ Bt,
                                                     const float* __restrict__ bias,
                                                     void* __restrict__ C,
                                                     int M, int N, int K, int nbx) {
    __shared__ __align__(16) ushort Asl[4 * 8192];   // 64 KB (4 slots x 16KB, 256 rows)
    __shared__ __align__(16) ushort Bsl[4 * 4096];   // 32 KB (4 slots x 8KB, 128 rows)

    const int t    = threadIdx.x;        // 0..511
    const int lane = t & 63;
    const int w    = t >> 6;             // 0..7
    const int m    = lane & 15;
    const int quad = lane >> 4;
    const int wm   = w >> 1;             // 0..3 (M quarter, 64 rows)
    const int wn   = w & 1;              // 0..1 (N half, 64 cols)

    const int nwg = gridDim.x;
    const int cpx = nwg >> 3;
    const int swz = ((int)blockIdx.x & 7) * cpx + ((int)blockIdx.x >> 3);
    const int bx  = swz % nbx;
    const int by  = swz / nbx;
    const int m0  = by * 256, n0 = bx * 128;

    const int r16s  = (t >> 2) & 15;
    const int kels  = ((t & 3) ^ ((t & 32) ? 2 : 0)) * 8;
    const int row0s = ((t >> 6) << 4) + r16s;
    const int row1s = row0s + 128;

    const int foff = m * 32 + ((quad * 8) ^ ((m & 8) ? 16 : 0));

#define STAGE(T_) do { int _s = (T_) & 3; \
    __builtin_amdgcn_global_load_lds( \
        (const __attribute__((address_space(1))) unsigned int*)(A + (size_t)(m0 + row0s) * K + (T_) * 32 + kels), \
        (__attribute__((address_space(3))) unsigned int*)(Asl + _s * 8192 + t * 8), 16, 0, 0); \
    __builtin_amdgcn_global_load_lds( \
        (const __attribute__((address_space(1))) unsigned int*)(A + (size_t)(m0 + row1s) * K + (T_) * 32 + kels), \
        (__attribute__((address_space(3))) unsigned int*)(Asl + _s * 8192 + (512 + t) * 8), 16, 0, 0); \
    __builtin_amdgcn_global_load_lds( \
        (const __attribute__((address_space(1))) unsigned int*)(Bt + (size_t)(n0 + row0s) * K + (T_) * 32 + kels), \
        (__attribute__((address_space(3))) unsigned int*)(Bsl + _s * 4096 + t * 8), 16, 0, 0); } while (0)

    f32x4 acc[4][4];
    #pragma unroll
    for (int i = 0; i < 4; ++i)
        #pragma unroll
        for (int j = 0; j < 4; ++j) acc[i][j] = (f32x4){0.f, 0.f, 0.f, 0.f};

    const int NT = K >> 5;               // 64 for K=2048

    STAGE(0); STAGE(1); STAGE(2);
    asm volatile("s_waitcnt vmcnt(6)" ::: "memory");
    __builtin_amdgcn_s_barrier();

    for (int T = 0; T < NT; ++T) {
        const int slot = T & 3;
        const ushort* as = Asl + slot * 8192 + wm * 2048;
        const ushort* bs = Bsl + slot * 4096 + wn * 2048;

        bf16x8 af[4], bf[4];
        #pragma unroll
        for (int mt = 0; mt < 4; ++mt)
            af[mt] = *(const bf16x8*)(as + mt * 512 + foff);
        #pragma unroll
        for (int nt = 0; nt < 4; ++nt)
            bf[nt] = *(const bf16x8*)(bs + nt * 512 + foff);

        if (T + 3 < NT) STAGE(T + 3);

        if (T + 3 < NT)      asm volatile("s_waitcnt vmcnt(6)" ::: "memory");
        else if (T + 2 < NT) asm volatile("s_waitcnt vmcnt(3)" ::: "memory");
        else                 asm volatile("s_waitcnt vmcnt(0)" ::: "memory");
        __builtin_amdgcn_s_barrier();
        asm volatile("s_waitcnt lgkmcnt(0)" ::: "memory");
        __builtin_amdgcn_s_setprio(1);
        #pragma unroll
        for (int mt = 0; mt < 4; ++mt)
            #pragma unroll
            for (int nt = 0; nt < 4; ++nt)
                acc[mt][nt] = __builtin_amdgcn_mfma_f32_16x16x32_bf16(af[mt], bf[nt], acc[mt][nt], 0, 0, 0);
        __builtin_amdgcn_s_setprio(0);
        __builtin_amdgcn_s_barrier();
    }
#undef STAGE

    float bcol[4];
    #pragma unroll
    for (int nt = 0; nt < 4; ++nt) bcol[nt] = bias[n0 + wn * 64 + nt * 16 + m];
    #pragma unroll
    for (int mt = 0; mt < 4; ++mt) {
        #pragma unroll
        for (int nt = 0; nt < 4; ++nt) {
            #pragma unroll
            for (int r = 0; r < 4; ++r) {
                int row = m0 + wm * 64 + mt * 16 + quad * 4 + r;
                int col = n0 + wn * 64 + nt * 16 + m;
                float v = acc[mt][nt][r] + bcol[nt];
                if (WRITE_BF16) ((ushort*)C)[(size_t)row * N + col] = f2bf(v);
                else            ((float*)C)[(size_t)row * N + col] = v;
            }
        }
    }
}

// ================= fused prep: RoPE Q/K tiles + V^T tiles (LDS transpose) =================
// blocks [0,4096): prep_qk (unchanged logic); [4096,5120): prep_v via coalesced
// row loads -> LDS transpose -> coalesced tile store (replaces the old
// 8-lines-per-instruction global gather).
__global__ __launch_bounds__(256) void prep_qkv(const ushort* __restrict__ qkvb,
                                                const int* __restrict__ pos_ids,
                                                ushort* __restrict__ Qt,
                                                ushort* __restrict__ Kt,
                                                ushort* __restrict__ Vtt) {
    __shared__ ushort vlds[64 * 136];   // 17.4 KB, row pad 136; col-swizzled
    int bid = blockIdx.x;
    int t   = threadIdx.x;

    if (bid < 4096) {
        // ---------- prep_qk ----------
        const float scale = 0.08838834764831845f;
        const float nl2b = -0.20762050593046014f;   // -log2(10000)/64
        int idx = bid * 256 + t;
        int p    = idx & 15;
        int r    = (idx >> 4) & 63;
        int tile = (idx >> 10) & 31;
        int h    = (idx >> 15) & 15;
        int b    = idx >> 19;
        int c    = p ^ (r & 15);
        int l    = tile * 64 + r;
        int half = c >> 3, cl = c & 7;
        const ushort* row = qkvb + (size_t)(b * LL + l) * N3E;
        float pos = (float)pos_ids[b * LL + l];

        bf16x8 qa = *(const bf16x8*)(row + h * HD + c * 8);
        bf16x8 qb = *(const bf16x8*)(row + h * HD + (c ^ 8) * 8);
        bf16x8 ka = *(const bf16x8*)(row + EE + h * HD + c * 8);
        bf16x8 kb = *(const bf16x8*)(row + EE + h * HD + (c ^ 8) * 8);
        bf16x8 qo, ko;
        #pragma unroll
        for (int i = 0; i < 8; ++i) {
            int j = cl * 8 + i;
            float ang = pos * exp2f((float)j * nl2b);
            float s, cs;
            sincosf(ang, &s, &cs);
            float sgn = half ? s : -s;
            float q1 = bf2f((ushort)qa[i]), q2 = bf2f((ushort)qb[i]);
            float k1 = bf2f((ushort)ka[i]), k2 = bf2f((ushort)kb[i]);
            qo[i] = (short)f2bf((q1 * cs + q2 * sgn) * scale);
            ko[i] = (short)f2bf(k1 * cs + k2 * sgn);
        }
        size_t obase = ((size_t)(b * 16 + h) * 32 + tile) * 8192 + r * 128 + p * 8;
        *(bf16x8*)(Qt + obase) = qo;
        *(bf16x8*)(Kt + obase) = ko;
    } else {
        // ---------- prep_v: one block per (bh, tile) ----------
        int vb   = bid - 4096;           // 0..1023
        int tile = vb & 31;
        int bh   = vb >> 5;
        int b    = bh >> 4, h = bh & 15;

        // load phase: rows kk in [0,64), cols d in [0,128) of V-head, coalesced
        #pragma unroll
        for (int it = 0; it < 4; ++it) {
            int c4 = t + it * 256;
            int kk = c4 >> 4, dc = c4 & 15;
            bf16x8 v = *(const bf16x8*)(qkvb + (size_t)(b * LL + tile * 64 + kk) * N3E
                                        + 2 * EE + h * HD + dc * 8);
            int colp = (dc * 8) ^ ((kk >> 3) << 4);   // col-swizzle by (kk>>3)&7
            *(bf16x8*)(vlds + kk * 136 + colp) = v;
        }
        __syncthreads();
        // store phase: output chunk (r,p): o[i] = V[kk=(p^(r&7))*8+i][r]
        #pragma unroll
        for (int it = 0; it < 4; ++it) {
            int oc = t + it * 256;
            int p = oc & 7, r = oc >> 3;             // r in [0,128)
            int c = p ^ (r & 7);
            bf16x8 o;
            #pragma unroll
            for (int i = 0; i < 8; ++i) {
                int kk = c * 8 + i;
                o[i] = (short)vlds[kk * 136 + (r ^ ((kk >> 3) << 4))];
            }
            *(bf16x8*)(Vtt + ((size_t)bh * 32 + tile) * 8192 + r * 64 + p * 8) = o;
        }
    }
}

// ---------------- Flash attention v2: split-barrier staging + defer-max (T13) ----------------
#define PSTR 68

__global__ __launch_bounds__(256, 2) void flash2(const ushort* __restrict__ Qt,
                                                 const ushort* __restrict__ Kt,
                                                 const ushort* __restrict__ Vtt,
                                                 ushort* __restrict__ y) {
    __shared__ __align__(16) ushort Ks[64 * 128];
    __shared__ __align__(16) ushort Vs[128 * 64];
    __shared__ __align__(16) ushort Ps[4 * 32 * PSTR];

    const int t    = threadIdx.x;
    const int w    = t >> 6;
    const int lane = t & 63;
    const int m    = lane & 15;
    const int quad = lane >> 4;
    const int qblk = blockIdx.x;
    const int bh   = blockIdx.y;
    const int b    = bh >> 4, h = bh & 15;

    const ushort* Qhead = Qt  + (size_t)bh * 32 * 8192;
    const ushort* Khead = Kt  + (size_t)bh * 32 * 8192;
    const ushort* Vhead = Vtt + (size_t)bh * 32 * 8192;

    bf16x8 qf[2][4];
    #pragma unroll
    for (int mt = 0; mt < 2; ++mt) {
        int rloc = w * 32 + mt * 16 + m;
        const ushort* qtile = Qhead + (size_t)(qblk * 2 + (rloc >> 6)) * 8192
                              + (rloc & 63) * 128;
        #pragma unroll
        for (int ks = 0; ks < 4; ++ks)
            qf[mt][ks] = *(const bf16x8*)(qtile + ((ks * 4 + quad) ^ m) * 8);
    }

    f32x4 oacc[2][8];
    #pragma unroll
    for (int mt = 0; mt < 2; ++mt)
        #pragma unroll
        for (int dt = 0; dt < 8; ++dt) oacc[mt][dt] = (f32x4){0.f, 0.f, 0.f, 0.f};
    float m_i[8], l_pl[8];
    #pragma unroll
    for (int s = 0; s < 8; ++s) { m_i[s] = -INFINITY; l_pl[s] = 0.f; }

    {
        const ushort* ksrc = Khead;
        #pragma unroll
        for (int i = 0; i < 4; ++i) {
            int cid = t + i * 256;
            __builtin_amdgcn_global_load_lds(
                (const __attribute__((address_space(1))) unsigned int*)(ksrc + cid * 8),
                (__attribute__((address_space(3))) unsigned int*)(Ks + cid * 8),
                16, 0, 0);
        }
    }

    for (int kt = 0; kt < 32; ++kt) {
        asm volatile("s_waitcnt vmcnt(0)\n\ts_barrier" ::: "memory");

        {
            const ushort* vsrc = Vhead + (size_t)kt * 8192;
            #pragma unroll
            for (int i = 0; i < 4; ++i) {
                int cid = t + i * 256;
                __builtin_amdgcn_global_load_lds(
                    (const __attribute__((address_space(1))) unsigned int*)(vsrc + cid * 8),
                    (__attribute__((address_space(3))) unsigned int*)(Vs + cid * 8),
                    16, 0, 0);
            }
        }

        f32x4 sacc[2][4];
        #pragma unroll
        for (int mt = 0; mt < 2; ++mt)
            #pragma unroll
            for (int nt = 0; nt < 4; ++nt) sacc[mt][nt] = (f32x4){0.f, 0.f, 0.f, 0.f};
        __builtin_amdgcn_s_setprio(1);
        #pragma unroll
        for (int ks = 0; ks < 4; ++ks) {
            #pragma unroll
            for (int nt = 0; nt < 4; ++nt) {
                bf16x8 kf = *(const bf16x8*)&Ks[(nt * 16 + m) * 128 + (((ks * 4 + quad) ^ m)) * 8];
                sacc[0][nt] = __builtin_amdgcn_mfma_f32_16x16x32_bf16(qf[0][ks], kf, sacc[0][nt], 0, 0, 0);
                sacc[1][nt] = __builtin_amdgcn_mfma_f32_16x16x32_bf16(qf[1][ks], kf, sacc[1][nt], 0, 0, 0);
            }
        }
        __builtin_amdgcn_s_setprio(0);

        // ---- online softmax with defer-max (skip rescale when max growth <= 8) ----
        float mxs[2][4];
        #pragma unroll
        for (int mt = 0; mt < 2; ++mt) {
            #pragma unroll
            for (int r = 0; r < 4; ++r) {
                float mx = fmaxf(fmaxf(sacc[mt][0][r], sacc[mt][1][r]),
                                 fmaxf(sacc[mt][2][r], sacc[mt][3][r]));
                #pragma unroll
                for (int off = 1; off < 16; off <<= 1) mx = fmaxf(mx, __shfl_xor(mx, off, 64));
                mxs[mt][r] = mx;
            }
        }
        int small = 1;
        #pragma unroll
        for (int mt = 0; mt < 2; ++mt)
            #pragma unroll
            for (int r = 0; r < 4; ++r)
                small &= (mxs[mt][r] <= m_i[mt * 4 + r] + 8.0f) ? 1 : 0;

        if (__all(small)) {
            // deferred path: keep old max, no alpha, no O-rescale
            #pragma unroll
            for (int mt = 0; mt < 2; ++mt) {
                #pragma unroll
                for (int r = 0; r < 4; ++r) {
                    int slot = mt * 4 + r;
                    float mnew = m_i[slot];
                    float rs = 0.f;
                    #pragma unroll
                    for (int nt = 0; nt < 4; ++nt) {
                        float pv = __expf(sacc[mt][nt][r] - mnew);
                        sacc[mt][nt][r] = pv;
                        rs += pv;
                    }
                    l_pl[slot] += rs;
                }
            }
        } else {
            float alpha_s[2][4];
            #pragma unroll
            for (int mt = 0; mt < 2; ++mt) {
                #pragma unroll
                for (int r = 0; r < 4; ++r) {
                    int slot = mt * 4 + r;
                    float mnew = fmaxf(m_i[slot], mxs[mt][r]);
                    float al = __expf(m_i[slot] - mnew);
                    m_i[slot] = mnew;
                    float rs = 0.f;
                    #pragma unroll
                    for (int nt = 0; nt < 4; ++nt) {
                        float pv = __expf(sacc[mt][nt][r] - mnew);
                        sacc[mt][nt][r] = pv;
                        rs += pv;
                    }
                    l_pl[slot] = l_pl[slot] * al + rs;
                    alpha_s[mt][r] = al;
                }
            }
            #pragma unroll
            for (int mt = 0; mt < 2; ++mt)
                #pragma unroll
                for (int dt = 0; dt < 8; ++dt)
                    #pragma unroll
                    for (int r = 0; r < 4; ++r) oacc[mt][dt][r] *= alpha_s[mt][r];
        }

        #pragma unroll
        for (int mt = 0; mt < 2; ++mt)
            #pragma unroll
            for (int nt = 0; nt < 4; ++nt)
                #pragma unroll
                for (int r = 0; r < 4; ++r)
                    Ps[w * 32 * PSTR + (mt * 16 + quad * 4 + r) * PSTR + nt * 16 + m]
                        = f2bf(sacc[mt][nt][r]);

        asm volatile("s_waitcnt vmcnt(0)\n\ts_barrier" ::: "memory");

        if (kt + 1 < 32) {
            const ushort* ksrc = Khead + (size_t)(kt + 1) * 8192;
            #pragma unroll
            for (int i = 0; i < 4; ++i) {
                int cid = t + i * 256;
                __builtin_amdgcn_global_load_lds(
                    (const __attribute__((address_space(1))) unsigned int*)(ksrc + cid * 8),
                    (__attribute__((address_space(3))) unsigned int*)(Ks + cid * 8),
                    16, 0, 0);
            }
        }

        __builtin_amdgcn_s_setprio(1);
        #pragma unroll
        for (int ks2 = 0; ks2 < 2; ++ks2) {
            bf16x8 pf0 = *(const bf16x8*)&Ps[w * 32 * PSTR + (0 * 16 + m) * PSTR + ks2 * 32 + quad * 8];
            bf16x8 pf1 = *(const bf16x8*)&Ps[w * 32 * PSTR + (1 * 16 + m) * PSTR + ks2 * 32 + quad * 8];
            #pragma unroll
            for (int dt = 0; dt < 8; ++dt) {
                bf16x8 vf = *(const bf16x8*)&Vs[(dt * 16 + m) * 64 + (((ks2 * 4 + quad) ^ (m & 7))) * 8];
                oacc[0][dt] = __builtin_amdgcn_mfma_f32_16x16x32_bf16(pf0, vf, oacc[0][dt], 0, 0, 0);
                oacc[1][dt] = __builtin_amdgcn_mfma_f32_16x16x32_bf16(pf1, vf, oacc[1][dt], 0, 0, 0);
            }
        }
        __builtin_amdgcn_s_setprio(0);
    }

    #pragma unroll
    for (int s = 0; s < 8; ++s) {
        #pragma unroll
        for (int off = 1; off < 16; off <<= 1) l_pl[s] += __shfl_xor(l_pl[s], off, 64);
        l_pl[s] = 1.0f / l_pl[s];
    }
    #pragma unroll
    for (int mt = 0; mt < 2; ++mt) {
        #pragma unroll
        for (int dt = 0; dt < 8; ++dt) {
            #pragma unroll
            for (int r = 0; r < 4; ++r) {
                int row = qblk * 128 + w * 32 + mt * 16 + quad * 4 + r;
                y[(size_t)(b * LL + row) * EE + h * HD + dt * 16 + m]
                    = f2bf(oacc[mt][dt][r] * l_pl[mt * 4 + r]);
            }
        }
    }
}

extern "C" void kernel_launch(void* const* d_in, const int* in_sizes, int n_in,
                              void* d_out, int out_size, void* d_ws, size_t ws_size,
                              hipStream_t stream) {
    const float* x      = (const float*)d_in[0];
    const int*   pos    = (const int*)d_in[1];
    const float* W_attn = (const float*)d_in[2];
    const float* b_attn = (const float*)d_in[3];
    const float* W_proj = (const float*)d_in[4];
    const float* b_proj = (const float*)d_in[5];
    float* out = (float*)d_out;

    const int M = BB * LL;   // 4096
    ushort* xb   = (ushort*)d_ws;                    // [M][E]      (→ Qt after gemm1)
    ushort* Wat  = xb   + (size_t)M * EE;            // [3E][E]     (→ yb after prep)
    ushort* Wpt  = Wat  + (size_t)N3E * EE;          // [E][E]
    ushort* qkvb = Wpt  + (size_t)EE * EE;           // [M][3E]
    ushort* Kt   = qkvb + (size_t)M * N3E;           // tiles
    ushort* Vtt  = Kt   + (size_t)M * EE;            // tiles
    ushort* Qt   = xb;                               // alias
    ushort* yb   = Wat;                              // alias

    // 1: fused cvt + weight transposes
    pre_all<<<dim3(NB_CVT + NB_T1 + NB_T2), dim3(256), 0, stream>>>(
        x, xb, W_attn, Wat, W_proj, Wpt);

    // 2: QKV projection (256x128 ring-4, bx-fast, 768 wg = 3 exact rounds)
    gemm_ktile<1><<<dim3((M / 256) * (N3E / 128)), dim3(512), 0, stream>>>(
        xb, Wat, b_attn, qkvb, M, N3E, EE, N3E / 128);

    // 3: fused RoPE Q/K tiles + V^T tiles
    prep_qkv<<<dim3(4096 + 1024), dim3(256), 0, stream>>>(qkvb, pos, Qt, Kt, Vtt);

    // 4: attention
    flash2<<<dim3(LL / 128, BB * HH), dim3(256), 0, stream>>>(Qt, Kt, Vtt, yb);

    // 5: out projection (256 wg = 1 exact round)
    gemm_ktile<0><<<dim3((M / 256) * (EE / 128)), dim3(512), 0, stream>>>(
        yb, Wpt, b_proj, out, M, EE, EE, EE / 128);
}

// Round 7
// 453.869 us; speedup vs baseline: 1.0292x; 1.0292x over previous
//
#include <hip/hip_runtime.h>
#include <math.h>

#define BB 2
#define LL 2048
#define EE 2048
#define HH 16
#define HD 128
#define N3E (3*EE)   // 6144

typedef __attribute__((ext_vector_type(8))) short  bf16x8;
typedef __attribute__((ext_vector_type(4))) float  f32x4;

__device__ __forceinline__ ushort f2bf(float f) {
    union { float f; unsigned u; } v; v.f = f;
    unsigned u = v.u + 0x7FFFu + ((v.u >> 16) & 1u);   // RNE
    return (ushort)(u >> 16);
}
__device__ __forceinline__ float bf2f(ushort u) {
    union { unsigned u; float f; } v; v.u = ((unsigned)u) << 16;
    return v.f;
}

// ================= fused pre-pass: cvt(x) + transpose(W_attn) + transpose(W_proj) =================
#define NB_CVT 4096
#define NB_T1  12288
#define NB_T2  4096

__device__ __forceinline__ void tr_block(const float* __restrict__ in,
                                         ushort* __restrict__ out,
                                         int R, int Ccol, int bx, int by,
                                         float (*tile)[33], int t) {
    int c0 = bx * 32, r0 = by * 32;
    int lr = t >> 5, lc = t & 31;
    #pragma unroll
    for (int i = 0; i < 4; ++i)
        tile[lr + i * 8][lc] = in[(size_t)(r0 + lr + i * 8) * Ccol + c0 + lc];
    __syncthreads();
    #pragma unroll
    for (int i = 0; i < 4; ++i)
        out[(size_t)(c0 + lr + i * 8) * R + r0 + lc] = f2bf(tile[lc][lr + i * 8]);
}

__global__ __launch_bounds__(256) void pre_all(const float* __restrict__ x,
                                               ushort* __restrict__ xb,
                                               const float* __restrict__ W_attn,
                                               ushort* __restrict__ Wat,
                                               const float* __restrict__ W_proj,
                                               ushort* __restrict__ Wpt) {
    __shared__ float tile[32][33];
    int bid = blockIdx.x;
    int t = threadIdx.x;
    if (bid < NB_CVT) {
        int i = (bid * 256 + t) * 8;
        float4 a = *(const float4*)(x + i);
        float4 b = *(const float4*)(x + i + 4);
        ushort4 p0 = { f2bf(a.x), f2bf(a.y), f2bf(a.z), f2bf(a.w) };
        ushort4 p1 = { f2bf(b.x), f2bf(b.y), f2bf(b.z), f2bf(b.w) };
        *(ushort4*)(xb + i)     = p0;
        *(ushort4*)(xb + i + 4) = p1;
    } else if (bid < NB_CVT + NB_T1) {
        int lb = bid - NB_CVT;
        tr_block(W_attn, Wat, EE, N3E, lb % (N3E / 32), lb / (N3E / 32), tile, t);
    } else {
        int lb = bid - NB_CVT - NB_T1;
        tr_block(W_proj, Wpt, EE, EE, lb % (EE / 32), lb / (EE / 32), tile, t);
    }
}

// ========== 256x128 8-wave GEMM, ring-4, counted-vmcnt (FROZEN since round 5) ==========
template<int WRITE_BF16>
__global__ __launch_bounds__(512, 2) void gemm_ktile(const ushort* __restrict__ A,
                                                     const ushort* __restrict__ Bt,
                                                     const float* __restrict__ bias,
                                                     void* __restrict__ C,
                                                     int M, int N, int K, int nbx) {
    __shared__ __align__(16) ushort Asl[4 * 8192];   // 64 KB (4 slots x 16KB, 256 rows)
    __shared__ __align__(16) ushort Bsl[4 * 4096];   // 32 KB (4 slots x 8KB, 128 rows)

    const int t    = threadIdx.x;        // 0..511
    const int lane = t & 63;
    const int w    = t >> 6;             // 0..7
    const int m    = lane & 15;
    const int quad = lane >> 4;
    const int wm   = w >> 1;             // 0..3 (M quarter, 64 rows)
    const int wn   = w & 1;              // 0..1 (N half, 64 cols)

    const int nwg = gridDim.x;
    const int cpx = nwg >> 3;
    const int swz = ((int)blockIdx.x & 7) * cpx + ((int)blockIdx.x >> 3);
    const int bx  = swz % nbx;
    const int by  = swz / nbx;
    const int m0  = by * 256, n0 = bx * 128;

    const int r16s  = (t >> 2) & 15;
    const int kels  = ((t & 3) ^ ((t & 32) ? 2 : 0)) * 8;
    const int row0s = ((t >> 6) << 4) + r16s;
    const int row1s = row0s + 128;

    const int foff = m * 32 + ((quad * 8) ^ ((m & 8) ? 16 : 0));

#define STAGE(T_) do { int _s = (T_) & 3; \
    __builtin_amdgcn_global_load_lds( \
        (const __attribute__((address_space(1))) unsigned int*)(A + (size_t)(m0 + row0s) * K + (T_) * 32 + kels), \
        (__attribute__((address_space(3))) unsigned int*)(Asl + _s * 8192 + t * 8), 16, 0, 0); \
    __builtin_amdgcn_global_load_lds( \
        (const __attribute__((address_space(1))) unsigned int*)(A + (size_t)(m0 + row1s) * K + (T_) * 32 + kels), \
        (__attribute__((address_space(3))) unsigned int*)(Asl + _s * 8192 + (512 + t) * 8), 16, 0, 0); \
    __builtin_amdgcn_global_load_lds( \
        (const __attribute__((address_space(1))) unsigned int*)(Bt + (size_t)(n0 + row0s) * K + (T_) * 32 + kels), \
        (__attribute__((address_space(3))) unsigned int*)(Bsl + _s * 4096 + t * 8), 16, 0, 0); } while (0)

    f32x4 acc[4][4];
    #pragma unroll
    for (int i = 0; i < 4; ++i)
        #pragma unroll
        for (int j = 0; j < 4; ++j) acc[i][j] = (f32x4){0.f, 0.f, 0.f, 0.f};

    const int NT = K >> 5;               // 64 for K=2048

    STAGE(0); STAGE(1); STAGE(2);
    asm volatile("s_waitcnt vmcnt(6)" ::: "memory");
    __builtin_amdgcn_s_barrier();

    for (int T = 0; T < NT; ++T) {
        const int slot = T & 3;
        const ushort* as = Asl + slot * 8192 + wm * 2048;
        const ushort* bs = Bsl + slot * 4096 + wn * 2048;

        bf16x8 af[4], bf[4];
        #pragma unroll
        for (int mt = 0; mt < 4; ++mt)
            af[mt] = *(const bf16x8*)(as + mt * 512 + foff);
        #pragma unroll
        for (int nt = 0; nt < 4; ++nt)
            bf[nt] = *(const bf16x8*)(bs + nt * 512 + foff);

        if (T + 3 < NT) STAGE(T + 3);

        if (T + 3 < NT)      asm volatile("s_waitcnt vmcnt(6)" ::: "memory");
        else if (T + 2 < NT) asm volatile("s_waitcnt vmcnt(3)" ::: "memory");
        else                 asm volatile("s_waitcnt vmcnt(0)" ::: "memory");
        __builtin_amdgcn_s_barrier();
        asm volatile("s_waitcnt lgkmcnt(0)" ::: "memory");
        __builtin_amdgcn_s_setprio(1);
        #pragma unroll
        for (int mt = 0; mt < 4; ++mt)
            #pragma unroll
            for (int nt = 0; nt < 4; ++nt)
                acc[mt][nt] = __builtin_amdgcn_mfma_f32_16x16x32_bf16(af[mt], bf[nt], acc[mt][nt], 0, 0, 0);
        __builtin_amdgcn_s_setprio(0);
        __builtin_amdgcn_s_barrier();
    }
#undef STAGE

    float bcol[4];
    #pragma unroll
    for (int nt = 0; nt < 4; ++nt) bcol[nt] = bias[n0 + wn * 64 + nt * 16 + m];
    #pragma unroll
    for (int mt = 0; mt < 4; ++mt) {
        #pragma unroll
        for (int nt = 0; nt < 4; ++nt) {
            #pragma unroll
            for (int r = 0; r < 4; ++r) {
                int row = m0 + wm * 64 + mt * 16 + quad * 4 + r;
                int col = n0 + wn * 64 + nt * 16 + m;
                float v = acc[mt][nt][r] + bcol[nt];
                if (WRITE_BF16) ((ushort*)C)[(size_t)row * N + col] = f2bf(v);
                else            ((float*)C)[(size_t)row * N + col] = v;
            }
        }
    }
}

// ================= fused prep: RoPE Q/K tiles + V^T tiles (LDS transpose) =================
__global__ __launch_bounds__(256) void prep_qkv(const ushort* __restrict__ qkvb,
                                                const int* __restrict__ pos_ids,
                                                ushort* __restrict__ Qt,
                                                ushort* __restrict__ Kt,
                                                ushort* __restrict__ Vtt) {
    __shared__ ushort vlds[64 * 136];   // 17.4 KB, row pad 136; col-swizzled
    int bid = blockIdx.x;
    int t   = threadIdx.x;

    if (bid < 4096) {
        // ---------- prep_qk ----------
        const float scale = 0.08838834764831845f;
        const float nl2b = -0.20762050593046014f;   // -log2(10000)/64
        int idx = bid * 256 + t;
        int p    = idx & 15;
        int r    = (idx >> 4) & 63;
        int tile = (idx >> 10) & 31;
        int h    = (idx >> 15) & 15;
        int b    = idx >> 19;
        int c    = p ^ (r & 15);
        int l    = tile * 64 + r;
        int half = c >> 3, cl = c & 7;
        const ushort* row = qkvb + (size_t)(b * LL + l) * N3E;
        float pos = (float)pos_ids[b * LL + l];

        bf16x8 qa = *(const bf16x8*)(row + h * HD + c * 8);
        bf16x8 qb = *(const bf16x8*)(row + h * HD + (c ^ 8) * 8);
        bf16x8 ka = *(const bf16x8*)(row + EE + h * HD + c * 8);
        bf16x8 kb = *(const bf16x8*)(row + EE + h * HD + (c ^ 8) * 8);
        bf16x8 qo, ko;
        #pragma unroll
        for (int i = 0; i < 8; ++i) {
            int j = cl * 8 + i;
            float ang = pos * exp2f((float)j * nl2b);
            float s, cs;
            sincosf(ang, &s, &cs);
            float sgn = half ? s : -s;
            float q1 = bf2f((ushort)qa[i]), q2 = bf2f((ushort)qb[i]);
            float k1 = bf2f((ushort)ka[i]), k2 = bf2f((ushort)kb[i]);
            qo[i] = (short)f2bf((q1 * cs + q2 * sgn) * scale);
            ko[i] = (short)f2bf(k1 * cs + k2 * sgn);
        }
        size_t obase = ((size_t)(b * 16 + h) * 32 + tile) * 8192 + r * 128 + p * 8;
        *(bf16x8*)(Qt + obase) = qo;
        *(bf16x8*)(Kt + obase) = ko;
    } else {
        // ---------- prep_v: one block per (bh, tile) ----------
        int vb   = bid - 4096;           // 0..1023
        int tile = vb & 31;
        int bh   = vb >> 5;
        int b    = bh >> 4, h = bh & 15;

        #pragma unroll
        for (int it = 0; it < 4; ++it) {
            int c4 = t + it * 256;
            int kk = c4 >> 4, dc = c4 & 15;
            bf16x8 v = *(const bf16x8*)(qkvb + (size_t)(b * LL + tile * 64 + kk) * N3E
                                        + 2 * EE + h * HD + dc * 8);
            int colp = (dc * 8) ^ ((kk >> 3) << 4);   // col-swizzle by (kk>>3)&7
            *(bf16x8*)(vlds + kk * 136 + colp) = v;
        }
        __syncthreads();
        #pragma unroll
        for (int it = 0; it < 4; ++it) {
            int oc = t + it * 256;
            int p = oc & 7, r = oc >> 3;             // r in [0,128)
            int c = p ^ (r & 7);
            bf16x8 o;
            #pragma unroll
            for (int i = 0; i < 8; ++i) {
                int kk = c * 8 + i;
                o[i] = (short)vlds[kk * 136 + (r ^ ((kk >> 3) << 4))];
            }
            *(bf16x8*)(Vtt + ((size_t)bh * 32 + tile) * 8192 + r * 64 + p * 8) = o;
        }
    }
}

// ---------------- Flash attention v3: barrier-free, direct-from-L2 K/V ----------------
// Round-7 change: K/V per head = 512 KB each (L2-fit; 16 KB tiles L1-fit across
// the block's 4 waves), and Kt/Vtt are pre-tiled in EXACT fragment layout with
// perfectly-coalesced direct reads (16 rows x one aligned 64B line per instr).
// So LDS staging + the two vmcnt(0)+barrier drains per K-tile were pure
// overhead (Common-mistake #7).  This version has ZERO barriers and ZERO
// K/V LDS: waves run independently; all waits are compiler-managed register
// load waits.  Ps (wave-private P layout conversion) is the only LDS.
// Defer-max REVERTED (round-6: cost ~20 us, prediction wrong).
#define PSTR 68

__global__ __launch_bounds__(256, 2) void flash2(const ushort* __restrict__ Qt,
                                                 const ushort* __restrict__ Kt,
                                                 const ushort* __restrict__ Vtt,
                                                 ushort* __restrict__ y) {
    __shared__ __align__(16) ushort Ps[4 * 32 * PSTR];   // 17.4 KB, wave-private slices

    const int t    = threadIdx.x;
    const int w    = t >> 6;
    const int lane = t & 63;
    const int m    = lane & 15;
    const int quad = lane >> 4;
    const int qblk = blockIdx.x;
    const int bh   = blockIdx.y;
    const int b    = bh >> 4, h = bh & 15;

    const ushort* Qhead = Qt  + (size_t)bh * 32 * 8192;
    const ushort* Khead = Kt  + (size_t)bh * 32 * 8192;
    const ushort* Vhead = Vtt + (size_t)bh * 32 * 8192;

    // ---- Q A-frags direct from global (one-time) ----
    bf16x8 qf[2][4];
    #pragma unroll
    for (int mt = 0; mt < 2; ++mt) {
        int rloc = w * 32 + mt * 16 + m;
        const ushort* qtile = Qhead + (size_t)(qblk * 2 + (rloc >> 6)) * 8192
                              + (rloc & 63) * 128;
        #pragma unroll
        for (int ks = 0; ks < 4; ++ks)
            qf[mt][ks] = *(const bf16x8*)(qtile + ((ks * 4 + quad) ^ m) * 8);
    }

    f32x4 oacc[2][8];
    #pragma unroll
    for (int mt = 0; mt < 2; ++mt)
        #pragma unroll
        for (int dt = 0; dt < 8; ++dt) oacc[mt][dt] = (f32x4){0.f, 0.f, 0.f, 0.f};
    float m_i[8], l_pl[8];
    #pragma unroll
    for (int s = 0; s < 8; ++s) { m_i[s] = -INFINITY; l_pl[s] = 0.f; }

    for (int kt = 0; kt < 32; ++kt) {
        const ushort* ktile = Khead + (size_t)kt * 8192;
        const ushort* vtile = Vhead + (size_t)kt * 8192;

        // ---- S = Q @ K^T : kf frags straight from L1/L2 ----
        f32x4 sacc[2][4];
        #pragma unroll
        for (int mt = 0; mt < 2; ++mt)
            #pragma unroll
            for (int nt = 0; nt < 4; ++nt) sacc[mt][nt] = (f32x4){0.f, 0.f, 0.f, 0.f};
        #pragma unroll
        for (int ks = 0; ks < 4; ++ks) {
            #pragma unroll
            for (int nt = 0; nt < 4; ++nt) {
                bf16x8 kf = *(const bf16x8*)(ktile + (nt * 16 + m) * 128
                                             + (((ks * 4 + quad) ^ m)) * 8);
                sacc[0][nt] = __builtin_amdgcn_mfma_f32_16x16x32_bf16(qf[0][ks], kf, sacc[0][nt], 0, 0, 0);
                sacc[1][nt] = __builtin_amdgcn_mfma_f32_16x16x32_bf16(qf[1][ks], kf, sacc[1][nt], 0, 0, 0);
            }
        }

        // ---- online softmax (deferred l cross-lane reduction) ----
        float alpha_s[2][4];
        #pragma unroll
        for (int mt = 0; mt < 2; ++mt) {
            #pragma unroll
            for (int r = 0; r < 4; ++r) {
                int slot = mt * 4 + r;
                float mx = fmaxf(fmaxf(sacc[mt][0][r], sacc[mt][1][r]),
                                 fmaxf(sacc[mt][2][r], sacc[mt][3][r]));
                #pragma unroll
                for (int off = 1; off < 16; off <<= 1) mx = fmaxf(mx, __shfl_xor(mx, off, 64));
                float mnew = fmaxf(m_i[slot], mx);
                float al = __expf(m_i[slot] - mnew);
                m_i[slot] = mnew;
                float rs = 0.f;
                #pragma unroll
                for (int nt = 0; nt < 4; ++nt) {
                    float pv = __expf(sacc[mt][nt][r] - mnew);
                    sacc[mt][nt][r] = pv;
                    rs += pv;
                }
                l_pl[slot] = l_pl[slot] * al + rs;
                alpha_s[mt][r] = al;
            }
        }
        #pragma unroll
        for (int mt = 0; mt < 2; ++mt)
            #pragma unroll
            for (int dt = 0; dt < 8; ++dt)
                #pragma unroll
                for (int r = 0; r < 4; ++r) oacc[mt][dt][r] *= alpha_s[mt][r];

        // ---- P -> LDS (wave-private; C-layout -> A-layout) ----
        #pragma unroll
        for (int mt = 0; mt < 2; ++mt)
            #pragma unroll
            for (int nt = 0; nt < 4; ++nt)
                #pragma unroll
                for (int r = 0; r < 4; ++r)
                    Ps[w * 32 * PSTR + (mt * 16 + quad * 4 + r) * PSTR + nt * 16 + m]
                        = f2bf(sacc[mt][nt][r]);

        // ---- O += P @ V : vf frags straight from L1/L2 ----
        #pragma unroll
        for (int ks2 = 0; ks2 < 2; ++ks2) {
            bf16x8 pf0 = *(const bf16x8*)&Ps[w * 32 * PSTR + (0 * 16 + m) * PSTR + ks2 * 32 + quad * 8];
            bf16x8 pf1 = *(const bf16x8*)&Ps[w * 32 * PSTR + (1 * 16 + m) * PSTR + ks2 * 32 + quad * 8];
            #pragma unroll
            for (int dt = 0; dt < 8; ++dt) {
                bf16x8 vf = *(const bf16x8*)(vtile + (dt * 16 + m) * 64
                                             + (((ks2 * 4 + quad) ^ (m & 7))) * 8);
                oacc[0][dt] = __builtin_amdgcn_mfma_f32_16x16x32_bf16(pf0, vf, oacc[0][dt], 0, 0, 0);
                oacc[1][dt] = __builtin_amdgcn_mfma_f32_16x16x32_bf16(pf1, vf, oacc[1][dt], 0, 0, 0);
            }
        }
    }

    // ---- epilogue: finish l reduction, normalize, write ----
    #pragma unroll
    for (int s = 0; s < 8; ++s) {
        #pragma unroll
        for (int off = 1; off < 16; off <<= 1) l_pl[s] += __shfl_xor(l_pl[s], off, 64);
        l_pl[s] = 1.0f / l_pl[s];
    }
    #pragma unroll
    for (int mt = 0; mt < 2; ++mt) {
        #pragma unroll
        for (int dt = 0; dt < 8; ++dt) {
            #pragma unroll
            for (int r = 0; r < 4; ++r) {
                int row = qblk * 128 + w * 32 + mt * 16 + quad * 4 + r;
                y[(size_t)(b * LL + row) * EE + h * HD + dt * 16 + m]
                    = f2bf(oacc[mt][dt][r] * l_pl[mt * 4 + r]);
            }
        }
    }
}

extern "C" void kernel_launch(void* const* d_in, const int* in_sizes, int n_in,
                              void* d_out, int out_size, void* d_ws, size_t ws_size,
                              hipStream_t stream) {
    const float* x      = (const float*)d_in[0];
    const int*   pos    = (const int*)d_in[1];
    const float* W_attn = (const float*)d_in[2];
    const float* b_attn = (const float*)d_in[3];
    const float* W_proj = (const float*)d_in[4];
    const float* b_proj = (const float*)d_in[5];
    float* out = (float*)d_out;

    const int M = BB * LL;   // 4096
    ushort* xb   = (ushort*)d_ws;                    // [M][E]      (→ Qt after gemm1)
    ushort* Wat  = xb   + (size_t)M * EE;            // [3E][E]     (→ yb after prep)
    ushort* Wpt  = Wat  + (size_t)N3E * EE;          // [E][E]
    ushort* qkvb = Wpt  + (size_t)EE * EE;           // [M][3E]
    ushort* Kt   = qkvb + (size_t)M * N3E;           // tiles
    ushort* Vtt  = Kt   + (size_t)M * EE;            // tiles
    ushort* Qt   = xb;                               // alias
    ushort* yb   = Wat;                              // alias

    // 1: fused cvt + weight transposes
    pre_all<<<dim3(NB_CVT + NB_T1 + NB_T2), dim3(256), 0, stream>>>(
        x, xb, W_attn, Wat, W_proj, Wpt);

    // 2: QKV projection (256x128 ring-4, bx-fast, 768 wg = 3 exact rounds)
    gemm_ktile<1><<<dim3((M / 256) * (N3E / 128)), dim3(512), 0, stream>>>(
        xb, Wat, b_attn, qkvb, M, N3E, EE, N3E / 128);

    // 3: fused RoPE Q/K tiles + V^T tiles
    prep_qkv<<<dim3(4096 + 1024), dim3(256), 0, stream>>>(qkvb, pos, Qt, Kt, Vtt);

    // 4: attention (barrier-free)
    flash2<<<dim3(LL / 128, BB * HH), dim3(256), 0, stream>>>(Qt, Kt, Vtt, yb);

    // 5: out projection (256 wg = 1 exact round)
    gemm_ktile<0><<<dim3((M / 256) * (EE / 128)), dim3(512), 0, stream>>>(
        yb, Wpt, b_proj, out, M, EE, EE, EE / 128);
}